// Round 1
// baseline (307.776 us; speedup 1.0000x reference)
//
#include <hip/hip_runtime.h>

#define Bb   4
#define Hh   16
#define Ss   2048
#define Dd   128
#define QBLK 128
#define KVB  64
#define NW   4

typedef __attribute__((ext_vector_type(8))) short bf16x8;
typedef __attribute__((ext_vector_type(4))) short short4v;
typedef __attribute__((ext_vector_type(4))) float f32x4;
typedef __attribute__((ext_vector_type(4))) float fvec4;

__device__ __forceinline__ unsigned short f2bf(float x) {
    union { float f; unsigned u; } c; c.f = x;
    unsigned r = c.u + 0x7FFFu + ((c.u >> 16) & 1u);   // RNE to bf16
    return (unsigned short)(r >> 16);
}

// ---------------- kernel 1: per-(b,h) mean of V over all S rows ----------------
__global__ __launch_bounds__(1024) void vmean_kernel(const float* __restrict__ V,
                                                     float* __restrict__ vm) {
    int bh = blockIdx.x, tid = threadIdx.x;
    int d4 = tid & 31, rg = tid >> 5;                  // 32 float4-cols, 32 row groups
    const fvec4* p = (const fvec4*)(V + (size_t)bh * Ss * Dd) + d4;
    fvec4 s = {0.f, 0.f, 0.f, 0.f};
    int r0 = rg * 64;
    for (int r = 0; r < 64; ++r) {
        fvec4 v = p[(size_t)(r0 + r) * 32];
        s += v;
    }
    __shared__ fvec4 red[1024];
    red[tid] = s;
    __syncthreads();
    for (int off = 512; off >= 32; off >>= 1) {
        if (tid < off) red[tid] += red[tid + off];
        __syncthreads();
    }
    if (tid < 32) {
        fvec4 a = red[tid] * (1.0f / 2048.0f);
        ((fvec4*)(vm + bh * Dd))[tid] = a;
    }
}

// ---------------- kernel 2: flash attention ----------------
__global__ __launch_bounds__(256, 2) void attn_kernel(
    const float* __restrict__ Qg, const float* __restrict__ Kg,
    const float* __restrict__ Vg, const int* __restrict__ slen,
    const float* __restrict__ vmean, float* __restrict__ Og)
{
    __shared__ __align__(16) short Ks[KVB * Dd];       // 16KB, [k][d] bf16, XOR (k&7)<<4
    __shared__ __align__(16) short Vt[Dd * KVB];       // 16KB, [d][k] bf16, XOR (d&15)<<3
    __shared__ __align__(16) short Ps[NW * 32 * KVB];  // 16KB, per-wave [q][k] bf16, XOR (q&7)<<4

    const int bid = blockIdx.x;
    const int xcd = bid & 7, j = bid >> 3;
    const int bh = xcd * 8 + (j >> 4);                 // cluster q-tiles of one bh per XCD
    const int qt = j & 15;
    const int b  = bh >> 4;
    const int len = slen[b];
    const int q0 = qt * QBLK;
    const int tid = threadIdx.x;

    // fully-invalid block: every row is the uniform-softmax mean of V
    if (q0 >= len) {
        int d = tid & 127;
        float val = vmean[bh * Dd + d];
        float* obase = Og + ((size_t)bh * Ss + q0) * Dd + d;
        int r0 = tid >> 7;
        #pragma unroll
        for (int i = 0; i < 64; ++i) obase[(size_t)(r0 + 2 * i) * Dd] = val;
        return;
    }

    const int w = tid >> 6, lane = tid & 63;
    const int g = lane >> 4, qc = lane & 15;
    const int qw0 = q0 + w * 32;
    const bool wave_active = (qw0 < len);

    // Q fragments, pre-scaled by log2(e)/sqrt(128)
    const float SC = 0.12752870368768582f;
    bf16x8 qf[2][4];
    #pragma unroll
    for (int t2 = 0; t2 < 2; ++t2) {
        const float* qrow = Qg + ((size_t)bh * Ss + (qw0 + 16 * t2 + qc)) * Dd;
        #pragma unroll
        for (int kc = 0; kc < 4; ++kc) {
            const fvec4* p = (const fvec4*)(qrow + kc * 32 + g * 8);
            fvec4 a = p[0], bvec = p[1];
            bf16x8 f;
            f[0] = f2bf(a[0] * SC); f[1] = f2bf(a[1] * SC);
            f[2] = f2bf(a[2] * SC); f[3] = f2bf(a[3] * SC);
            f[4] = f2bf(bvec[0] * SC); f[5] = f2bf(bvec[1] * SC);
            f[6] = f2bf(bvec[2] * SC); f[7] = f2bf(bvec[3] * SC);
            qf[t2][kc] = f;
        }
    }

    f32x4 o[2][8];
    #pragma unroll
    for (int t2 = 0; t2 < 2; ++t2)
        #pragma unroll
        for (int dt = 0; dt < 8; ++dt) o[t2][dt] = (f32x4){0.f, 0.f, 0.f, 0.f};
    float m_[2]   = {-3e38f, -3e38f};
    float lsum[2] = {0.f, 0.f};

    const int kv_end   = min(q0 + QBLK, len);
    const int kv_end_w = min(qw0 + 32, kv_end);
    const int nt = (kv_end + KVB - 1) >> 6;

    char* PsB = (char*)Ps + w * 4096;

    for (int tile = 0; tile < nt; ++tile) {
        const int kv0 = tile * KVB;
        __syncthreads();
        // ---- stage K (row-major bf16, swizzled) ----
        {
            const fvec4* src = (const fvec4*)(Kg + ((size_t)bh * Ss + kv0) * Dd);
            #pragma unroll
            for (int i = 0; i < 8; ++i) {
                int f = tid + 256 * i;
                int kr = f >> 5, d4 = f & 31;
                fvec4 v = src[(size_t)kr * 32 + d4];
                short4v sv;
                sv[0] = f2bf(v[0]); sv[1] = f2bf(v[1]);
                sv[2] = f2bf(v[2]); sv[3] = f2bf(v[3]);
                int byteoff = (kr * 256 + d4 * 8) ^ ((kr & 7) << 4);
                *(short4v*)((char*)Ks + byteoff) = sv;
            }
        }
        // ---- stage V transposed ([d][k] bf16, swizzled) ----
        {
            const float* src = Vg + ((size_t)bh * Ss + kv0) * Dd;
            #pragma unroll
            for (int i = 0; i < 2; ++i) {
                int idx = tid + 256 * i;
                int dt4 = idx & 31, kt4 = idx >> 5;
                int d0 = dt4 * 4, k0 = kt4 * 4;
                fvec4 vv[4];
                #pragma unroll
                for (int jj = 0; jj < 4; ++jj)
                    vv[jj] = ((const fvec4*)(src + (size_t)(k0 + jj) * Dd))[dt4];
                #pragma unroll
                for (int jj = 0; jj < 4; ++jj) {
                    short4v sv;
                    sv[0] = f2bf(vv[0][jj]); sv[1] = f2bf(vv[1][jj]);
                    sv[2] = f2bf(vv[2][jj]); sv[3] = f2bf(vv[3][jj]);
                    int d = d0 + jj;
                    int byteoff = (d * 128 + k0 * 2) ^ ((d & 15) << 3);
                    *(short4v*)((char*)Vt + byteoff) = sv;
                }
            }
        }
        __syncthreads();

        if (wave_active && kv0 < kv_end_w) {
            // ---- swapped QK^T: S^T[k][q] = K·Q^T ----
            f32x4 sa[2][4];
            #pragma unroll
            for (int t2 = 0; t2 < 2; ++t2)
                #pragma unroll
                for (int mt = 0; mt < 4; ++mt) sa[t2][mt] = (f32x4){0.f, 0.f, 0.f, 0.f};
            #pragma unroll
            for (int mt = 0; mt < 4; ++mt) {
                bf16x8 kf[4];
                #pragma unroll
                for (int kc = 0; kc < 4; ++kc) {
                    int row = mt * 16 + qc;
                    int byteoff = (row * 256 + kc * 64 + g * 16) ^ ((row & 7) << 4);
                    kf[kc] = *(const bf16x8*)((const char*)Ks + byteoff);
                }
                #pragma unroll
                for (int t2 = 0; t2 < 2; ++t2)
                    #pragma unroll
                    for (int kc = 0; kc < 4; ++kc)
                        sa[t2][mt] = __builtin_amdgcn_mfma_f32_16x16x32_bf16(
                            kf[kc], qf[t2][kc], sa[t2][mt], 0, 0, 0);
            }

            // ---- mask + online softmax (per lane: one q-row per t2) ----
            #pragma unroll
            for (int t2 = 0; t2 < 2; ++t2) {
                const int qrow = qw0 + 16 * t2 + qc;
                const bool full = (kv0 + KVB - 1) <= (qw0 + 16 * t2);
                float z[16];
                #pragma unroll
                for (int mt = 0; mt < 4; ++mt)
                    #pragma unroll
                    for (int r = 0; r < 4; ++r) {
                        float sv = sa[t2][mt][r];
                        if (!full) {
                            int kk = kv0 + mt * 16 + g * 4 + r;
                            sv = (kk <= qrow) ? sv : -3e38f;
                        }
                        z[mt * 4 + r] = sv;
                    }
                float tm = z[0];
                #pragma unroll
                for (int i2 = 1; i2 < 16; ++i2) tm = fmaxf(tm, z[i2]);
                tm = fmaxf(tm, __shfl_xor(tm, 16));
                tm = fmaxf(tm, __shfl_xor(tm, 32));
                float mnew = fmaxf(m_[t2], tm);
                float al = exp2f(m_[t2] - mnew);
                m_[t2] = mnew;
                float ls = 0.f;
                float pv[16];
                #pragma unroll
                for (int i2 = 0; i2 < 16; ++i2) {
                    float p = exp2f(z[i2] - mnew);
                    pv[i2] = p; ls += p;
                }
                lsum[t2] = lsum[t2] * al + ls;
                // write P (bf16 pairs) to per-wave LDS
                int prow = t2 * 16 + qc;
                #pragma unroll
                for (int mt = 0; mt < 4; ++mt)
                    #pragma unroll
                    for (int jj = 0; jj < 2; ++jj) {
                        unsigned pk = (unsigned)f2bf(pv[mt * 4 + jj * 2]) |
                                      ((unsigned)f2bf(pv[mt * 4 + jj * 2 + 1]) << 16);
                        int byteoff = (prow * 128 + mt * 32 + g * 8 + jj * 4) ^ ((prow & 7) << 4);
                        *(unsigned*)(PsB + byteoff) = pk;
                    }
                // rescale O accumulators (rows 4g+r need alpha of row (4g+r))
                #pragma unroll
                for (int r = 0; r < 4; ++r) {
                    float alr = __shfl(al, g * 4 + r);
                    #pragma unroll
                    for (int dt = 0; dt < 8; ++dt) o[t2][dt][r] *= alr;
                }
            }

            // ---- PV ----
            bf16x8 ap[2][2];
            #pragma unroll
            for (int t2 = 0; t2 < 2; ++t2)
                #pragma unroll
                for (int c = 0; c < 2; ++c) {
                    int prow = t2 * 16 + qc;
                    int byteoff = (prow * 128 + c * 64 + g * 16) ^ ((prow & 7) << 4);
                    ap[t2][c] = *(const bf16x8*)(PsB + byteoff);
                }
            #pragma unroll
            for (int dt = 0; dt < 8; ++dt) {
                int d = dt * 16 + qc;
                int swz = (d & 15) << 3;
                #pragma unroll
                for (int c = 0; c < 2; ++c) {
                    int base = d * 128 + c * 64 + g * 16;
                    short4v lo = *(const short4v*)((const char*)Vt + (base ^ swz));
                    short4v hi = *(const short4v*)((const char*)Vt + ((base + 8) ^ swz));
                    bf16x8 bfv = {lo[0], lo[1], lo[2], lo[3], hi[0], hi[1], hi[2], hi[3]};
                    #pragma unroll
                    for (int t2 = 0; t2 < 2; ++t2)
                        o[t2][dt] = __builtin_amdgcn_mfma_f32_16x16x32_bf16(
                            ap[t2][c], bfv, o[t2][dt], 0, 0, 0);
                }
            }
        }
    }

    // ---- epilogue: normalize, overwrite invalid rows with vmean, store ----
    float inv_[2][4];
    #pragma unroll
    for (int t2 = 0; t2 < 2; ++t2) {
        float L = lsum[t2];
        L += __shfl_xor(L, 16);
        L += __shfl_xor(L, 32);
        #pragma unroll
        for (int r = 0; r < 4; ++r) {
            float Lr = __shfl(L, g * 4 + r);
            inv_[t2][r] = 1.0f / Lr;
        }
    }
    bool needvm = (qw0 + 32 > len);
    float vmv[8];
    #pragma unroll
    for (int dt = 0; dt < 8; ++dt)
        vmv[dt] = needvm ? vmean[bh * Dd + dt * 16 + qc] : 0.f;
    #pragma unroll
    for (int t2 = 0; t2 < 2; ++t2)
        #pragma unroll
        for (int r = 0; r < 4; ++r) {
            int rowg = qw0 + t2 * 16 + g * 4 + r;
            float* orow = Og + ((size_t)bh * Ss + rowg) * Dd + qc;
            #pragma unroll
            for (int dt = 0; dt < 8; ++dt) {
                float val = o[t2][dt][r] * inv_[t2][r];
                if (rowg >= len) val = vmv[dt];
                orow[dt * 16] = val;
            }
        }
}

extern "C" void kernel_launch(void* const* d_in, const int* in_sizes, int n_in,
                              void* d_out, int out_size, void* d_ws, size_t ws_size,
                              hipStream_t stream) {
    const float* q  = (const float*)d_in[0];
    const float* k  = (const float*)d_in[1];
    const float* v  = (const float*)d_in[2];
    const int*   sl = (const int*)d_in[3];
    float* vm  = (float*)d_ws;     // 64*128 floats = 32KB
    float* out = (float*)d_out;
    vmean_kernel<<<dim3(Bb * Hh), dim3(1024), 0, stream>>>(v, vm);
    attn_kernel<<<dim3((Ss / QBLK) * Bb * Hh), dim3(256), 0, stream>>>(q, k, v, sl, vm, out);
}